// Round 11
// baseline (40.991 us; speedup 1.0000x reference)
//
#include <hip/hip_runtime.h>

#define HW 1024
#define TSTEPS 256
#define SIZE_NORM 5.65685424949238019521f

#define REP16(M)  M(0) M(1) M(2) M(3) M(4) M(5) M(6) M(7) M(8) M(9) M(10) M(11) M(12) M(13) M(14) M(15)
#define REP16D(M) M(15) M(14) M(13) M(12) M(11) M(10) M(9) M(8) M(7) M(6) M(5) M(4) M(3) M(2) M(1) M(0)

__device__ __forceinline__ unsigned umax2(unsigned a, unsigned b) { return a > b ? a : b; }
__device__ __forceinline__ unsigned umax3(unsigned a, unsigned b, unsigned c) {
    return umax2(umax2(a, b), c);   // v_max3_u32
}
__device__ __forceinline__ int imin2(int a, int b) { return a < b ? a : b; }

// bit-identical to all passing rounds
__device__ __forceinline__ float e_of(float g, float h) {
    float f = 0.5f * g + 0.5f * h;
    return expf(-f / SIZE_NORM);
}

#define DPP_MAX(v, ctrl)                                                                     \
    do {                                                                                     \
        unsigned _o = (unsigned)__builtin_amdgcn_mov_dpp((int)(v), (ctrl), 0xF, 0xF, false); \
        (v) = umax2((v), _o);                                                                \
    } while (0)

#define DPP_MIN(v, ctrl)                                                                     \
    do {                                                                                     \
        int _o = __builtin_amdgcn_mov_dpp((v), (ctrl), 0xF, 0xF, false);                     \
        (v) = imin2((v), _o);                                                                \
    } while (0)

__launch_bounds__(64)
__global__ void astar_kernel(const float* __restrict__ cost,
                             const float* __restrict__ start,
                             const float* __restrict__ goal,
                             const float* __restrict__ obst,
                             float* __restrict__ out) {
    __shared__ int   ls_par[HW];
    __shared__ unsigned char ls_m[HW];

    const int b    = blockIdx.x;
    const int lane = threadIdx.x;            // 0..63
    const float* costb  = cost  + b * HW;
    const float* startb = start + b * HW;
    const float* goalb  = goal  + b * HW;
    const float* obstb  = obst  + b * HW;

    const int rowbase = lane >> 5;           // 0/1
    const int col     = lane & 31;

    // ---- per-lane state: e, g, cst, h (64 regs) + masks ----
#define DECL_STATE(K) float cst##K, g##K, h##K; unsigned e##K;
    REP16(DECL_STATE)
#undef DECL_STATE
    unsigned openm = 0, histm = 0, obstm = 0, goalm = 0;

#define LOADK(K) { int c = (K)*64 + lane;                                  \
        cst##K = costb[c]; g##K = 0.0f;                                    \
        openm |= (startb[c] > 0.5f ? 1u : 0u) << (K);                      \
        obstm |= (obstb[c]  > 0.5f ? 1u : 0u) << (K);                      \
        goalm |= (goalb[c]  > 0.5f ? 1u : 0u) << (K); }
    REP16(LOADK)
#undef LOADK

    int gidx = 0;
#define GOALK(K) { unsigned long long m = __ballot((goalm >> (K)) & 1u);   \
        if (m) gidx = (K)*64 + (int)(__ffsll(m) - 1); }
    REP16D(GOALK)
#undef GOALK

    const float gi = (float)(gidx >> 5), gj = (float)(gidx & 31);
#define HINITK(K) { int c = (K)*64 + lane;                                 \
        float ci = (float)(c >> 5), cj = (float)(c & 31);                  \
        float dx = fabsf(ci - gi), dy = fabsf(cj - gj);                    \
        float hc = (dx + dy) - fminf(dx, dy);                              \
        float euc = sqrtf(dx * dx + dy * dy);                              \
        float heur = __fadd_rn(hc, __fmul_rn(0.001f, euc));                \
        h##K = __fadd_rn(heur, cst##K);                                    \
        e##K = ((openm >> (K)) & 1u) ? __float_as_uint(e_of(0.0f, h##K)) : 0u; \
        ls_par[c] = gidx; }
    REP16(HINITK)
#undef HINITK

    // slot-update body: K static (register index); si/k_s/lane_s DYNAMIC.
    // Out-of-range slot => rowok_ false for all lanes AND k_s!=K => no-op.
#define UPD(K) {                                                                   \
        const int di_ = (((K) << 1) + rowbase) - si;                               \
        const bool rowok_ = (unsigned)(di_ + 1) <= 2u;                             \
        const bool nb_ = rowok_ && colok && ((di_ != 0) || djnz) &&                \
                         (((obstm >> (K)) & 1u) != 0u);                            \
        const bool op_ = ((openm >> (K)) & 1u) != 0u;                              \
        const bool hs_ = ((histm >> (K)) & 1u) != 0u;                              \
        const bool sel_ = nb_ && ((!op_ && !hs_) || (op_ && (gval < g##K)));       \
        unsigned eN_ = __float_as_uint(e_of(gval, h##K));                          \
        if (sel_) ls_par[(K) * 64 + lane] = s_sel;                                 \
        chg = sel_ ? 1u : chg;                                                     \
        g##K = sel_ ? gval : g##K;                                                 \
        e##K = sel_ ? eN_ : e##K;                                                  \
        openm = sel_ ? (openm | (1u << (K))) : openm;                              \
        {                                                                          \
            const bool isl_ = (k_s == (K)) && (lane == lane_s);                    \
            chg = (isl_ && !hs_) ? 1u : chg;                                       \
            histm = isl_ ? (histm | (1u << (K))) : histm;                          \
            if (unsolved) {                                                        \
                openm = isl_ ? (openm & ~(1u << (K))) : openm;                     \
                e##K  = isl_ ? 0u : e##K;                                          \
            }                                                                      \
        } }

    // case body for slot pair (CA, CB): k_s is provably in {CA, CB}
#define CASEU(LBL, CA, CB)                                                            \
    case LBL: {                                                                       \
        const int gb0_ = __builtin_amdgcn_readlane(__float_as_int(g##CA),   lane_s);  \
        const int cb0_ = __builtin_amdgcn_readlane(__float_as_int(cst##CA), lane_s);  \
        const int gb1_ = __builtin_amdgcn_readlane(__float_as_int(g##CB),   lane_s);  \
        const int cb1_ = __builtin_amdgcn_readlane(__float_as_int(cst##CB), lane_s);  \
        const bool hi_ = (k_s != (CA));                                               \
        const float gval = __int_as_float(hi_ ? gb1_ : gb0_) +                        \
                           __int_as_float(hi_ ? cb1_ : cb0_);                         \
        UPD(CA)  UPD(CB)                                                              \
    } break;

    // ---- main scan: up to 256 steps, exact fixed-point early exit ----
    for (int step = 0; step < TSTEPS; ++step) {
        // phase A: gmax (max3 tree + DPP butterfly + 4 readlanes)
        unsigned m0 = umax3(e0,  e1,  e2);
        unsigned m1 = umax3(e3,  e4,  e5);
        unsigned m2 = umax3(e6,  e7,  e8);
        unsigned m3 = umax3(e9,  e10, e11);
        unsigned m4 = umax3(e12, e13, e14);
        unsigned lm = umax2(umax3(m0, m1, m2), umax3(m3, m4, e15));
        DPP_MAX(lm, 0xB1);    // quad_perm xor1
        DPP_MAX(lm, 0x4E);    // quad_perm xor2
        DPP_MAX(lm, 0x141);   // row_half_mirror
        DPP_MAX(lm, 0x128);   // row_ror:8
        unsigned r0 = (unsigned)__builtin_amdgcn_readlane((int)lm, 0);
        unsigned r1 = (unsigned)__builtin_amdgcn_readlane((int)lm, 16);
        unsigned r2 = (unsigned)__builtin_amdgcn_readlane((int)lm, 32);
        unsigned r3 = (unsigned)__builtin_amdgcn_readlane((int)lm, 48);
        const unsigned gmax = umax2(umax2(r0, r1), umax2(r2, r3));

        // phase B: min index among e==gmax, all-VALU (no ballots)
#define CD4(Ka, Kb, Kc, Kd, NOUT)                                                  \
        int NOUT; {                                                                \
            int ca_ = (e##Ka == gmax) ? ((Ka) * 64 + lane) : 0x7FFFFFFF;           \
            int cb2_ = (e##Kb == gmax) ? ((Kb) * 64 + lane) : 0x7FFFFFFF;          \
            int cc_ = (e##Kc == gmax) ? ((Kc) * 64 + lane) : 0x7FFFFFFF;           \
            int cd_ = (e##Kd == gmax) ? ((Kd) * 64 + lane) : 0x7FFFFFFF;           \
            NOUT = imin2(imin2(ca_, cb2_), imin2(cc_, cd_));                       \
        }
        CD4(0, 1, 2, 3,    n0_)
        CD4(4, 5, 6, 7,    n1_)
        CD4(8, 9, 10, 11,  n2_)
        CD4(12, 13, 14, 15, n3_)
#undef CD4
        int lmc = imin2(imin2(n0_, n1_), imin2(n2_, n3_));
        DPP_MIN(lmc, 0xB1);
        DPP_MIN(lmc, 0x4E);
        DPP_MIN(lmc, 0x141);
        DPP_MIN(lmc, 0x128);
        int q0 = __builtin_amdgcn_readlane(lmc, 0);
        int q1 = __builtin_amdgcn_readlane(lmc, 16);
        int q2 = __builtin_amdgcn_readlane(lmc, 32);
        int q3 = __builtin_amdgcn_readlane(lmc, 48);
        const int s_sel = imin2(imin2(q0, q1), imin2(q2, q3));

        const int si = s_sel >> 5, sj = s_sel & 31;
        const int lane_s = s_sel & 63, k_s = s_sel >> 6;
        const bool unsolved = (s_sel != gidx);
        const int dj = col - sj;
        const bool colok = (unsigned)(dj + 1) <= 2u;
        const bool djnz = (dj != 0);

        unsigned chg = 0;

        // 16-case jump table on k0; bodies handle (C, C+1) with natural
        // predication of the inactive slot (border cases verified no-op).
        const int k0 = (si > 0 ? si - 1 : 0) >> 1;
        switch (k0) {
            CASEU(0,  0,  1)
            CASEU(1,  1,  2)
            CASEU(2,  2,  3)
            CASEU(3,  3,  4)
            CASEU(4,  4,  5)
            CASEU(5,  5,  6)
            CASEU(6,  6,  7)
            CASEU(7,  7,  8)
            CASEU(8,  8,  9)
            CASEU(9,  9,  10)
            CASEU(10, 10, 11)
            CASEU(11, 11, 12)
            CASEU(12, 12, 13)
            CASEU(13, 13, 14)
            CASEU(14, 14, 15)
            CASEU(15, 14, 15)   // si==31 only: k_s=15 -> hi_ true; UPD(14) no-op
            default: break;
        }

        // exact fixed point: bit-exact early exit (proven in r10)
        if (!unsolved) {
            if (__ballot(chg != 0u) == 0ull) break;
        }
    }

    // ---- backtrack via pointer doubling (unchanged) ----
#define MINITK(K) { int c = (K)*64 + lane; ls_m[c] = (c == gidx) ? 1 : 0; }
    REP16(MINITK)
#undef MINITK
    __syncthreads();
    int A0 = ls_par[gidx];
    if (lane == 0) ls_m[A0] = 1;
    __syncthreads();

    for (int j = 0; j < 8; ++j) {            // 2^8 = 256 = TSTEPS
#define DECLBT(K) int pk##K, pp##K;
        REP16(DECLBT)
#undef DECLBT
        unsigned mk = 0;
#define BT1(K) pk##K = ls_par[(K)*64 + lane];
        REP16(BT1)
#undef BT1
#define BT2(K) pp##K = ls_par[pk##K];
        REP16(BT2)
#undef BT2
#define BT3(K) mk |= (unsigned)ls_m[(K)*64 + lane] << (K);
        REP16(BT3)
#undef BT3
        __syncthreads();
#define BT4(K) if ((mk >> (K)) & 1u) ls_m[pk##K] = 1;
        REP16(BT4)
#undef BT4
#define BT5(K) ls_par[(K)*64 + lane] = pp##K;
        REP16(BT5)
#undef BT5
        __syncthreads();
    }

    // ---- outputs: [histories | path], f32 0/1 ----
    float* hout = out + (size_t)b * HW;
    float* pout = out + (size_t)gridDim.x * HW + (size_t)b * HW;
#define OUTK(K) { int c = (K)*64 + lane;                                   \
        hout[c] = (float)((histm >> (K)) & 1u);                            \
        pout[c] = (float)ls_m[c]; }
    REP16(OUTK)
#undef OUTK
}

extern "C" void kernel_launch(void* const* d_in, const int* in_sizes, int n_in,
                              void* d_out, int out_size, void* d_ws, size_t ws_size,
                              hipStream_t stream) {
    (void)n_in; (void)d_ws; (void)ws_size; (void)out_size;
    const float* cost  = (const float*)d_in[0];
    const float* start = (const float*)d_in[1];
    const float* goal  = (const float*)d_in[2];
    const float* obst  = (const float*)d_in[3];
    float* out = (float*)d_out;
    const int nb = in_sizes[0] / HW;
    astar_kernel<<<dim3(nb), dim3(64), 0, stream>>>(cost, start, goal, obst, out);
}

// Round 12
// 40.687 us; speedup vs baseline: 1.0075x; 1.0075x over previous
//
#include <hip/hip_runtime.h>

#define HW 1024
#define TSTEPS 256
#define SIZE_NORM 5.65685424949238019521f

#define REP16(M)  M(0) M(1) M(2) M(3) M(4) M(5) M(6) M(7) M(8) M(9) M(10) M(11) M(12) M(13) M(14) M(15)
#define REP16D(M) M(15) M(14) M(13) M(12) M(11) M(10) M(9) M(8) M(7) M(6) M(5) M(4) M(3) M(2) M(1) M(0)

__device__ __forceinline__ int imin2(int a, int b) { return a < b ? a : b; }

// bit-identical to all passing rounds
__device__ __forceinline__ float e_of(float g, float h) {
    float f = 0.5f * g + 0.5f * h;
    return expf(-f / SIZE_NORM);
}

// exact (max e, min c) triple combine: key (hi,lo) as u64, gc rides along
#define PMX(HA, LA, GA, HB, LB, GB) {                                              \
        unsigned long long a_ = ((unsigned long long)(HA) << 32) | (LA);           \
        unsigned long long b_ = ((unsigned long long)(HB) << 32) | (LB);           \
        const bool t_ = b_ > a_;                                                   \
        HA = t_ ? (HB) : (HA); LA = t_ ? (LB) : (LA); GA = t_ ? (GB) : (GA); }

// one cross-lane stage: mov_dpp all three, combine (bound_ctrl=1 -> invalid=0;
// a (0,0) key never strictly wins, so acc is preserved on invalid lanes)
#define RST(ctrl) {                                                                          \
        unsigned oh_ = (unsigned)__builtin_amdgcn_mov_dpp((int)ph0, (ctrl), 0xF, 0xF, true); \
        unsigned ol_ = (unsigned)__builtin_amdgcn_mov_dpp((int)pl0, (ctrl), 0xF, 0xF, true); \
        int      og_ = __builtin_amdgcn_mov_dpp(pg0, (ctrl), 0xF, 0xF, true);                \
        PMX(ph0, pl0, pg0, oh_, ol_, og_) }

__launch_bounds__(64)
__global__ void astar_kernel(const float* __restrict__ cost,
                             const float* __restrict__ start,
                             const float* __restrict__ goal,
                             const float* __restrict__ obst,
                             float* __restrict__ out) {
    __shared__ int   ls_par[HW];
    __shared__ unsigned char ls_m[HW];

    const int b    = blockIdx.x;
    const int lane = threadIdx.x;            // 0..63
    const float* costb  = cost  + b * HW;
    const float* startb = start + b * HW;
    const float* goalb  = goal  + b * HW;
    const float* obstb  = obst  + b * HW;

    const int rowbase = lane >> 5;           // 0/1
    const int col     = lane & 31;
    const unsigned nl = 63 - lane;           // lo-key base: 1023-c = nl + (15-K)*64

    // ---- per-lane state: e, g, gc, cst, h (80 regs) + masks ----
#define DECL_STATE(K) float cst##K, g##K, h##K, gc##K; unsigned e##K;
    REP16(DECL_STATE)
#undef DECL_STATE
    unsigned openm = 0, histm = 0, obstm = 0, goalm = 0;

#define LOADK(K) { int c = (K)*64 + lane;                                  \
        cst##K = costb[c]; g##K = 0.0f;                                    \
        openm |= (startb[c] > 0.5f ? 1u : 0u) << (K);                      \
        obstm |= (obstb[c]  > 0.5f ? 1u : 0u) << (K);                      \
        goalm |= (goalb[c]  > 0.5f ? 1u : 0u) << (K); }
    REP16(LOADK)
#undef LOADK

    int gidx = 0;
#define GOALK(K) { unsigned long long m = __ballot((goalm >> (K)) & 1u);   \
        if (m) gidx = (K)*64 + (int)(__ffsll(m) - 1); }
    REP16D(GOALK)
#undef GOALK

    const float gi = (float)(gidx >> 5), gj = (float)(gidx & 31);
#define HINITK(K) { int c = (K)*64 + lane;                                 \
        float ci = (float)(c >> 5), cj = (float)(c & 31);                  \
        float dx = fabsf(ci - gi), dy = fabsf(cj - gj);                    \
        float hc = (dx + dy) - fminf(dx, dy);                              \
        float euc = sqrtf(dx * dx + dy * dy);                              \
        float heur = __fadd_rn(hc, __fmul_rn(0.001f, euc));                \
        h##K = __fadd_rn(heur, cst##K);                                    \
        e##K = ((openm >> (K)) & 1u) ? __float_as_uint(e_of(0.0f, h##K)) : 0u; \
        gc##K = cst##K;                      /* g=0 + cst */               \
        ls_par[c] = gidx; }
    REP16(HINITK)
#undef HINITK

    // slot-update body: K static; si/k_s/lane_s dynamic; gval from the reduce.
#define UPD(K) {                                                                   \
        const int di_ = (((K) << 1) + rowbase) - si;                               \
        const bool rowok_ = (unsigned)(di_ + 1) <= 2u;                             \
        const bool nb_ = rowok_ && colok && ((di_ != 0) || djnz) &&                \
                         (((obstm >> (K)) & 1u) != 0u);                            \
        const bool op_ = ((openm >> (K)) & 1u) != 0u;                              \
        const bool hs_ = ((histm >> (K)) & 1u) != 0u;                              \
        const bool sel_ = nb_ && ((!op_ && !hs_) || (op_ && (gval < g##K)));       \
        unsigned eN_ = __float_as_uint(e_of(gval, h##K));                          \
        float gcN_ = gval + cst##K;                                                \
        if (sel_) ls_par[(K) * 64 + lane] = s_sel;                                 \
        chg = sel_ ? 1u : chg;                                                     \
        g##K  = sel_ ? gval : g##K;                                                \
        gc##K = sel_ ? gcN_ : gc##K;                                               \
        e##K  = sel_ ? eN_ : e##K;                                                 \
        openm = sel_ ? (openm | (1u << (K))) : openm;                              \
        {                                                                          \
            const bool isl_ = (k_s == (K)) && (lane == lane_s);                    \
            chg = (isl_ && !hs_) ? 1u : chg;                                       \
            histm = isl_ ? (histm | (1u << (K))) : histm;                          \
            if (unsolved) {                                                        \
                openm = isl_ ? (openm & ~(1u << (K))) : openm;                     \
                e##K  = isl_ ? 0u : e##K;                                          \
            }                                                                      \
        } }

#define CASEU(LBL, CA, CB) case LBL: { UPD(CA) UPD(CB) } break;

    // ---- main scan: up to 256 steps, exact fixed-point early exit ----
    for (int step = 0; step < TSTEPS; ++step) {
        // fused (max e, min c, carry gc) reduction: local u64 tree + DPP ladder
#define PK(K) unsigned ph##K = e##K, pl##K = nl + (15 - (K)) * 64;                 \
        int pg##K = __float_as_int(gc##K);
        REP16(PK)
#undef PK
#define PM(A, B) PMX(ph##A, pl##A, pg##A, ph##B, pl##B, pg##B)
        PM(0, 1)   PM(2, 3)   PM(4, 5)   PM(6, 7)
        PM(8, 9)   PM(10, 11) PM(12, 13) PM(14, 15)
        PM(0, 2)   PM(4, 6)   PM(8, 10)  PM(12, 14)
        PM(0, 4)   PM(8, 12)
        PM(0, 8)
#undef PM
        // all-VALU 64-lane ladder, result lands in lane 63
        RST(0x111)   // row_shr:1
        RST(0x112)   // row_shr:2
        RST(0x114)   // row_shr:4
        RST(0x118)   // row_shr:8  -> lane15/31/47/63 hold row maxima
        RST(0x142)   // row_bcast:15 -> lane31 = max(0..31), lane63 = max(32..63)
        RST(0x143)   // row_bcast:31 -> lane63 = max(all 64)

        const int rl_idx = __builtin_amdgcn_readlane((int)pl0, 63);
        const int rl_gc  = __builtin_amdgcn_readlane(pg0, 63);
        const int s_sel  = 1023 - rl_idx;
        const float gval = __int_as_float(rl_gc);

        const int si = s_sel >> 5, sj = s_sel & 31;
        const int lane_s = s_sel & 63, k_s = s_sel >> 6;
        const bool unsolved = (s_sel != gidx);
        const int dj = col - sj;
        const bool colok = (unsigned)(dj + 1) <= 2u;
        const bool djnz = (dj != 0);

        unsigned chg = 0;

        // 16-case jump table on k0; bodies handle (C, C+1); inactive slot is a
        // natural no-op (rowok_ false for all lanes; k_s != K)
        const int k0 = (si > 0 ? si - 1 : 0) >> 1;
        switch (k0) {
            CASEU(0,  0,  1)
            CASEU(1,  1,  2)
            CASEU(2,  2,  3)
            CASEU(3,  3,  4)
            CASEU(4,  4,  5)
            CASEU(5,  5,  6)
            CASEU(6,  6,  7)
            CASEU(7,  7,  8)
            CASEU(8,  8,  9)
            CASEU(9,  9,  10)
            CASEU(10, 10, 11)
            CASEU(11, 11, 12)
            CASEU(12, 12, 13)
            CASEU(13, 13, 14)
            CASEU(14, 14, 15)
            CASEU(15, 14, 15)   // si==31: k_s=15; UPD(14) no-op
            default: break;
        }

        // exact fixed point: bit-exact early exit (proven in r10)
        if (!unsolved) {
            if (__ballot(chg != 0u) == 0ull) break;
        }
    }

    // ---- backtrack via pointer doubling (unchanged) ----
#define MINITK(K) { int c = (K)*64 + lane; ls_m[c] = (c == gidx) ? 1 : 0; }
    REP16(MINITK)
#undef MINITK
    __syncthreads();
    int A0 = ls_par[gidx];
    if (lane == 0) ls_m[A0] = 1;
    __syncthreads();

    for (int j = 0; j < 8; ++j) {            // 2^8 = 256 = TSTEPS
#define DECLBT(K) int pk##K, pp##K;
        REP16(DECLBT)
#undef DECLBT
        unsigned mk = 0;
#define BT1(K) pk##K = ls_par[(K)*64 + lane];
        REP16(BT1)
#undef BT1
#define BT2(K) pp##K = ls_par[pk##K];
        REP16(BT2)
#undef BT2
#define BT3(K) mk |= (unsigned)ls_m[(K)*64 + lane] << (K);
        REP16(BT3)
#undef BT3
        __syncthreads();
#define BT4(K) if ((mk >> (K)) & 1u) ls_m[pk##K] = 1;
        REP16(BT4)
#undef BT4
#define BT5(K) ls_par[(K)*64 + lane] = pp##K;
        REP16(BT5)
#undef BT5
        __syncthreads();
    }

    // ---- outputs: [histories | path], f32 0/1 ----
    float* hout = out + (size_t)b * HW;
    float* pout = out + (size_t)gridDim.x * HW + (size_t)b * HW;
#define OUTK(K) { int c = (K)*64 + lane;                                   \
        hout[c] = (float)((histm >> (K)) & 1u);                            \
        pout[c] = (float)ls_m[c]; }
    REP16(OUTK)
#undef OUTK
}

extern "C" void kernel_launch(void* const* d_in, const int* in_sizes, int n_in,
                              void* d_out, int out_size, void* d_ws, size_t ws_size,
                              hipStream_t stream) {
    (void)n_in; (void)d_ws; (void)ws_size; (void)out_size;
    const float* cost  = (const float*)d_in[0];
    const float* start = (const float*)d_in[1];
    const float* goal  = (const float*)d_in[2];
    const float* obst  = (const float*)d_in[3];
    float* out = (float*)d_out;
    const int nb = in_sizes[0] / HW;
    astar_kernel<<<dim3(nb), dim3(64), 0, stream>>>(cost, start, goal, obst, out);
}